// Round 1
// baseline (1344.888 us; speedup 1.0000x reference)
//
#include <hip/hip_runtime.h>
#include <hip/hip_bf16.h>

// UpBlock: 5 sparse gather-GEMM convs + LeakyReLU + BatchNorm + residual.
// Strategy: bf16 MFMA (16x16x32) with direct per-lane global gathers for A,
// packed bf16 weights [tap][co][ci] for B, fp32 accumulation, fused epilogues.

typedef __attribute__((ext_vector_type(8))) short bf16x8;
typedef __attribute__((ext_vector_type(4))) short short4v;
typedef __attribute__((ext_vector_type(4))) float f32x4;

__device__ __forceinline__ short f2bf(float f) {
    union { float f; unsigned u; } v; v.f = f;
    unsigned r = v.u + 0x7fffu + ((v.u >> 16) & 1u);
    return (short)(r >> 16);
}
__device__ __forceinline__ float bf2f(short s) {
    union { unsigned u; float f; } v;
    v.u = ((unsigned)(unsigned short)s) << 16;
    return v.f;
}

// ---------------- cast fp32 -> bf16 (vectorized 8/thread) ----------------
__global__ void cast_kernel(const float* __restrict__ in, short* __restrict__ out, int total) {
    int e = (blockIdx.x * blockDim.x + threadIdx.x) * 8;
    if (e >= total) return;
    bf16x8 r;
#pragma unroll
    for (int j = 0; j < 8; ++j) r[j] = f2bf(in[e + j]);
    *(bf16x8*)(out + e) = r;
}

// ------------- pack W[k][ci][co] fp32 -> Wp[k][co][ci] bf16 ---------------
__global__ void pack_w_kernel(const float* __restrict__ w, short* __restrict__ wp,
                              int CI, int total) {
    int t = blockIdx.x * blockDim.x + threadIdx.x;
    if (t >= total) return;
    int ci = t % CI;
    int rest = t / CI;
    int co = rest & 63;
    int k = rest >> 6;
    wp[t] = f2bf(w[(k * CI + ci) * 64 + co]);
}

// ---------------- gather-GEMM conv ----------------
// Each wave: 32 output rows x 64 cols. A gathered per-lane from global.
// EPI: 0 = leaky_relu -> bf16 out; 1 = +skip(fp32) -> bf16 out.
template <int CI, int KT, int EPI>
__global__ __launch_bounds__(256) void conv_kernel(
    const short* __restrict__ fin, const int* __restrict__ nbr,
    const short* __restrict__ wp, const float* __restrict__ skip,
    short* __restrict__ fout, int N)
{
    const int lane = threadIdx.x & 63;
    const int wid = threadIdx.x >> 6;
    const int lr = lane & 15;   // A row-in-tile / B,C col-in-tile
    const int lg = lane >> 4;   // lane group 0..3
    const int rowbase = blockIdx.x * 128 + wid * 32;

    int r0 = rowbase + lr;      if (r0 > N - 1) r0 = N - 1;
    int r1 = rowbase + 16 + lr; if (r1 > N - 1) r1 = N - 1;

    f32x4 acc[2][4];
#pragma unroll
    for (int t = 0; t < 2; ++t)
#pragma unroll
        for (int c = 0; c < 4; ++c) acc[t][c] = (f32x4)(0.f);

    const int koff = lg * 8;
    for (int k = 0; k < KT; ++k) {
        int i0 = nbr[r0 * KT + k];
        int i1 = nbr[r1 * KT + k];
        const short* a0 = fin + i0 * CI + koff;
        const short* a1 = fin + i1 * CI + koff;
        const short* bb = wp + (k * 64 + lr) * CI + koff;
#pragma unroll
        for (int s = 0; s < CI / 32; ++s) {
            bf16x8 av0 = *(const bf16x8*)(a0 + s * 32);
            bf16x8 av1 = *(const bf16x8*)(a1 + s * 32);
#pragma unroll
            for (int ct = 0; ct < 4; ++ct) {
                bf16x8 bv = *(const bf16x8*)(bb + ct * 16 * CI + s * 32);
                acc[0][ct] = __builtin_amdgcn_mfma_f32_16x16x32_bf16(av0, bv, acc[0][ct], 0, 0, 0);
                acc[1][ct] = __builtin_amdgcn_mfma_f32_16x16x32_bf16(av1, bv, acc[1][ct], 0, 0, 0);
            }
        }
    }

    // C/D layout: col = lane&15 (+16*ct), row = (lane>>4)*4 + reg (+16*t)
#pragma unroll
    for (int t = 0; t < 2; ++t) {
#pragma unroll
        for (int reg = 0; reg < 4; ++reg) {
            int r = rowbase + t * 16 + lg * 4 + reg;
            if (r < N) {
#pragma unroll
                for (int ct = 0; ct < 4; ++ct) {
                    int col = ct * 16 + lr;
                    float v = acc[t][ct][reg];
                    if (EPI == 0) {
                        v = v > 0.f ? v : 0.01f * v;
                    } else {
                        v += skip[(size_t)r * 64 + col];
                    }
                    fout[(size_t)r * 64 + col] = f2bf(v);
                }
            }
        }
    }
}

// -------------- per-channel sum / sumsq over [N][64] bf16 --------------
__global__ void stats_kernel(const short* __restrict__ f, int N, float* __restrict__ sums) {
    __shared__ float sm[128];
    if (threadIdx.x < 128) sm[threadIdx.x] = 0.f;
    __syncthreads();
    const int c4 = (threadIdx.x & 15) * 4;
    int row = blockIdx.x * 16 + (threadIdx.x >> 4);
    const int rstride = gridDim.x * 16;
    float s[4] = {0.f, 0.f, 0.f, 0.f};
    float q[4] = {0.f, 0.f, 0.f, 0.f};
    for (; row < N; row += rstride) {
        short4v v = *(const short4v*)(f + (size_t)row * 64 + c4);
#pragma unroll
        for (int j = 0; j < 4; ++j) {
            float x = bf2f(v[j]);
            s[j] += x;
            q[j] += x * x;
        }
    }
#pragma unroll
    for (int j = 0; j < 4; ++j) {
        atomicAdd(&sm[c4 + j], s[j]);
        atomicAdd(&sm[64 + c4 + j], q[j]);
    }
    __syncthreads();
    if (threadIdx.x < 128) atomicAdd(&sums[threadIdx.x], sm[threadIdx.x]);
}

// -------------- BN scale/shift from sums --------------
__global__ void finalize_kernel(const float* __restrict__ sums, const float* __restrict__ g,
                                const float* __restrict__ b, float invN, float* __restrict__ ss) {
    int c = threadIdx.x;
    float mean = sums[c] * invN;
    float var = sums[64 + c] * invN - mean * mean;
    float sc = g[c] * rsqrtf(var + 1e-5f);
    ss[c] = sc;
    ss[64 + c] = b[c] - mean * sc;
}

// -------------- apply scale/shift; OUTF: 0 -> bf16, 1 -> fp32 --------------
template <int OUTF>
__global__ void norm_kernel(const short* __restrict__ in, const float* __restrict__ ss,
                            void* __restrict__ outv, int total) {
    int e = (blockIdx.x * blockDim.x + threadIdx.x) * 8;
    if (e >= total) return;
    bf16x8 v = *(const bf16x8*)(in + e);
    int c0 = e & 63;
    if (OUTF) {
        float* out = (float*)outv;
#pragma unroll
        for (int j = 0; j < 8; ++j)
            out[e + j] = bf2f(v[j]) * ss[c0 + j] + ss[64 + c0 + j];
    } else {
        bf16x8 r;
#pragma unroll
        for (int j = 0; j < 8; ++j)
            r[j] = f2bf(bf2f(v[j]) * ss[c0 + j] + ss[64 + c0 + j]);
        *(bf16x8*)((short*)outv + e) = r;
    }
}

extern "C" void kernel_launch(void* const* d_in, const int* in_sizes, int n_in,
                              void* d_out, int out_size, void* d_ws, size_t ws_size,
                              hipStream_t stream) {
    const float* x    = (const float*)d_in[0];
    const float* skip = (const float*)d_in[1];
    const int* nbr1 = (const int*)d_in[2];
    const int* nbrU = (const int*)d_in[3];
    const int* nbr2 = (const int*)d_in[4];
    const int* nbr3 = (const int*)d_in[5];
    const int* nbr4 = (const int*)d_in[6];
    const float* W1 = (const float*)d_in[7];
    const float* WU = (const float*)d_in[8];
    const float* W2 = (const float*)d_in[9];
    const float* W3 = (const float*)d_in[10];
    const float* W4 = (const float*)d_in[11];
    const float* g1 = (const float*)d_in[12]; const float* b1 = (const float*)d_in[13];
    const float* g2 = (const float*)d_in[14]; const float* b2 = (const float*)d_in[15];
    const float* g3 = (const float*)d_in[16]; const float* b3 = (const float*)d_in[17];
    const float* g4 = (const float*)d_in[18]; const float* b4 = (const float*)d_in[19];

    const int Nl = in_sizes[0] / 128;  // 120000
    const int Nu = in_sizes[1] / 64;   // 240000

    char* ws = (char*)d_ws;
    size_t off = 0;
    auto alloc = [&](size_t bytes) -> char* {
        char* p = ws + off;
        off += (bytes + 255) & ~(size_t)255;
        return p;
    };
    const size_t fb = (size_t)Nu * 64 * 2;           // 30.72 MB feat buffer
    const size_t xb = (size_t)Nl * 128 * 2;          // x as bf16
    short* RA = (short*)alloc(xb > fb ? xb : fb);    // x_bf16, later reused
    size_t r1sz = 2 * (size_t)Nl * 64 * 2; if (fb > r1sz) r1sz = fb;
    short* R1 = (short*)alloc(r1sz);
    short* R2 = (short*)alloc(fb);
    short* Wp1 = (short*)alloc((size_t)27 * 128 * 64 * 2);
    short* WpU = (short*)alloc((size_t)27 * 64 * 64 * 2);
    short* Wp2 = (short*)alloc((size_t)9 * 64 * 64 * 2);
    short* Wp3 = (short*)alloc((size_t)9 * 64 * 64 * 2);
    short* Wp4 = (short*)alloc((size_t)27 * 64 * 64 * 2);
    float* sums = (float*)alloc(4 * 128 * sizeof(float));
    float* ss   = (float*)alloc(4 * 128 * sizeof(float));

    hipMemsetAsync(sums, 0, 4 * 128 * sizeof(float), stream);

    // cast x to bf16
    {
        int total = Nl * 128;
        cast_kernel<<<(total / 8 + 255) / 256, 256, 0, stream>>>(x, RA, total);
    }
    // pack weights to bf16 [k][co][ci]
    pack_w_kernel<<<(27 * 128 * 64 + 255) / 256, 256, 0, stream>>>(W1, Wp1, 128, 27 * 128 * 64);
    pack_w_kernel<<<(27 * 64 * 64 + 255) / 256, 256, 0, stream>>>(WU, WpU, 64, 27 * 64 * 64);
    pack_w_kernel<<<(9 * 64 * 64 + 255) / 256, 256, 0, stream>>>(W2, Wp2, 64, 9 * 64 * 64);
    pack_w_kernel<<<(9 * 64 * 64 + 255) / 256, 256, 0, stream>>>(W3, Wp3, 64, 9 * 64 * 64);
    pack_w_kernel<<<(27 * 64 * 64 + 255) / 256, 256, 0, stream>>>(W4, Wp4, 64, 27 * 64 * 64);

    short* F1raw = R1;
    short* F1n   = R1 + (size_t)Nl * 64;

    const int gl = (Nl + 127) / 128;
    const int gu = (Nu + 127) / 128;

    // stage 1: conv1 (Ci=128, K=27) + leaky -> BN
    conv_kernel<128, 27, 0><<<gl, 256, 0, stream>>>(RA, nbr1, Wp1, nullptr, F1raw, Nl);
    stats_kernel<<<1024, 256, 0, stream>>>(F1raw, Nl, sums + 0);
    finalize_kernel<<<1, 64, 0, stream>>>(sums + 0, g1, b1, 1.f / Nl, ss + 0);
    norm_kernel<0><<<(Nl * 64 / 8 + 255) / 256, 256, 0, stream>>>(F1raw, ss + 0, F1n, Nl * 64);

    // stage 2: inverse conv (K=27) + residual skip
    conv_kernel<64, 27, 1><<<gu, 256, 0, stream>>>(F1n, nbrU, WpU, skip, R2, Nu);

    // stage 3: conv2 (K=9) + leaky -> BN
    conv_kernel<64, 9, 0><<<gu, 256, 0, stream>>>(R2, nbr2, Wp2, nullptr, RA, Nu);
    stats_kernel<<<1024, 256, 0, stream>>>(RA, Nu, sums + 128);
    finalize_kernel<<<1, 64, 0, stream>>>(sums + 128, g2, b2, 1.f / Nu, ss + 128);
    norm_kernel<0><<<(Nu * 64 / 8 + 255) / 256, 256, 0, stream>>>(RA, ss + 128, R1, Nu * 64);

    // stage 4: conv3 (K=9) + leaky -> BN
    conv_kernel<64, 9, 0><<<gu, 256, 0, stream>>>(R1, nbr3, Wp3, nullptr, R2, Nu);
    stats_kernel<<<1024, 256, 0, stream>>>(R2, Nu, sums + 256);
    finalize_kernel<<<1, 64, 0, stream>>>(sums + 256, g3, b3, 1.f / Nu, ss + 256);
    norm_kernel<0><<<(Nu * 64 / 8 + 255) / 256, 256, 0, stream>>>(R2, ss + 256, RA, Nu * 64);

    // stage 5: conv4 (K=27) + leaky -> BN -> fp32 out
    conv_kernel<64, 27, 0><<<gu, 256, 0, stream>>>(RA, nbr4, Wp4, nullptr, R1, Nu);
    stats_kernel<<<1024, 256, 0, stream>>>(R1, Nu, sums + 384);
    finalize_kernel<<<1, 64, 0, stream>>>(sums + 384, g4, b4, 1.f / Nu, ss + 384);
    norm_kernel<1><<<(Nu * 64 / 8 + 255) / 256, 256, 0, stream>>>(R1, ss + 384, d_out, Nu * 64);
}

// Round 2
// 1279.450 us; speedup vs baseline: 1.0511x; 1.0511x over previous
//
#include <hip/hip_runtime.h>
#include <hip/hip_bf16.h>

// UpBlock: 5 sparse gather-GEMM convs + LeakyReLU + BatchNorm + residual.
// R1: latency-bound fix — LDS-staged rulebook, 4-slot gather pipeline,
// BN folded into next conv's weights (stats fused in conv epilogue).

typedef __attribute__((ext_vector_type(8))) short bf16x8;
typedef __attribute__((ext_vector_type(4))) float f32x4;

__device__ __forceinline__ short f2bf(float f) {
    union { float f; unsigned u; } v; v.f = f;
    unsigned r = v.u + 0x7fffu + ((v.u >> 16) & 1u);
    return (short)(r >> 16);
}
__device__ __forceinline__ float bf2f(short s) {
    union { unsigned u; float f; } v;
    v.u = ((unsigned)(unsigned short)s) << 16;
    return v.f;
}

// ---------------- cast fp32 -> bf16 (vectorized 8/thread) ----------------
__global__ void cast_kernel(const float* __restrict__ in, short* __restrict__ out, int total) {
    int e = (blockIdx.x * blockDim.x + threadIdx.x) * 8;
    if (e >= total) return;
    bf16x8 r;
#pragma unroll
    for (int j = 0; j < 8; ++j) r[j] = f2bf(in[e + j]);
    *(bf16x8*)(out + e) = r;
}

// ------ pack W[k][ci][co] fp32 -> Wp[k][co][ci] bf16, optional ci-scale ------
__global__ void pack_w_kernel(const float* __restrict__ w, short* __restrict__ wp,
                              const float* __restrict__ ss, int CI, int total) {
    int t = blockIdx.x * blockDim.x + threadIdx.x;
    if (t >= total) return;
    int ci = t % CI;
    int rest = t / CI;
    int co = rest & 63;
    int k = rest >> 6;
    float v = w[(k * CI + ci) * 64 + co];
    if (ss) v *= ss[ci];
    wp[t] = f2bf(v);
}

// ------ bias[co] += sum_ci sh[ci]*W[k][ci][co]; one block per tap k ------
__global__ void bias_kernel(const float* __restrict__ w, const float* __restrict__ ss,
                            int CI, float* __restrict__ bias) {
    int k = blockIdx.x;
    int co = threadIdx.x;
    float acc = 0.f;
    for (int ci = 0; ci < CI; ++ci)
        acc += ss[64 + ci] * w[(k * CI + ci) * 64 + co];
    atomicAdd(&bias[co], acc);
}

// ---------------- gather-GEMM conv ----------------
// 4 waves/block, 128 output rows/block, 32 rows/wave.
// MODE 0: v = leaky(acc[+bias]); write bf16; fused per-channel stats.
// MODE 1: v = acc + bias + skip; write bf16 (residual stage, no stats).
template <int CI, int KT, int MODE, bool HAS_BIAS>
__global__ __launch_bounds__(256) void conv_kernel(
    const short* __restrict__ fin, const int* __restrict__ nbr,
    const short* __restrict__ wp, const float* __restrict__ bias,
    const float* __restrict__ skip, short* __restrict__ fout,
    int N, float* __restrict__ sums)
{
    constexpr int S = CI / 32;   // 32-bf16 k-chunks per tap
    constexpr int T = KT * S;    // total pipeline chunks
    constexpr int PF = 4;        // gather slots in flight

    __shared__ int snbr[128 * KT];
    __shared__ float sred[128];

    const int tid = threadIdx.x;
    const int lane = tid & 63;
    const int wid = tid >> 6;
    const int lr = lane & 15;    // A row-in-tile / B,C col-in-tile
    const int lg = lane >> 4;    // lane group 0..3
    const int rowbase = blockIdx.x * 128;
    const int nrows = (N - rowbase < 128) ? (N - rowbase) : 128;

    for (int i = tid; i < nrows * KT; i += 256)
        snbr[i] = __builtin_nontemporal_load(&nbr[(size_t)rowbase * KT + i]);
    if (MODE == 0 && tid < 128) sred[tid] = 0.f;
    __syncthreads();

    const int rb0 = wid * 32 + lr;
    const int rb1 = wid * 32 + 16 + lr;
    const int row0 = (rb0 < nrows ? rb0 : nrows - 1);
    const int row1 = (rb1 < nrows ? rb1 : nrows - 1);
    const int koff = lg * 8;

    f32x4 acc[2][4];
#pragma unroll
    for (int t = 0; t < 2; ++t)
#pragma unroll
        for (int c = 0; c < 4; ++c) acc[t][c] = (f32x4)(0.f);

    bf16x8 sa0[PF], sa1[PF];

    // prologue: fill all PF slots
#pragma unroll
    for (int t = 0; t < PF; ++t) {
        const int k = t / S, s = t % S;
        const int i0 = snbr[row0 * KT + k];
        const int i1 = snbr[row1 * KT + k];
        sa0[t] = *(const bf16x8*)(fin + (size_t)i0 * CI + s * 32 + koff);
        sa1[t] = *(const bf16x8*)(fin + (size_t)i1 * CI + s * 32 + koff);
    }

#pragma unroll
    for (int t = 0; t < T; ++t) {
        const int k = t / S, s = t % S;
        const int slot = t % PF;
        const short* bb = wp + ((size_t)k * 64 + lr) * CI + s * 32 + koff;
#pragma unroll
        for (int ct = 0; ct < 4; ++ct) {
            bf16x8 bv = *(const bf16x8*)(bb + (size_t)ct * 16 * CI);
            acc[0][ct] = __builtin_amdgcn_mfma_f32_16x16x32_bf16(sa0[slot], bv, acc[0][ct], 0, 0, 0);
            acc[1][ct] = __builtin_amdgcn_mfma_f32_16x16x32_bf16(sa1[slot], bv, acc[1][ct], 0, 0, 0);
        }
        // refill consumed slot for chunk t+PF
        if (t + PF < T) {
            const int k2 = (t + PF) / S, s2 = (t + PF) % S;
            const int i0 = snbr[row0 * KT + k2];
            const int i1 = snbr[row1 * KT + k2];
            sa0[slot] = *(const bf16x8*)(fin + (size_t)i0 * CI + s2 * 32 + koff);
            sa1[slot] = *(const bf16x8*)(fin + (size_t)i1 * CI + s2 * 32 + koff);
        }
    }

    // epilogue: C/D layout col = ct*16+lr, row = wid*32 + t*16 + lg*4 + reg
    float bia[4] = {0.f, 0.f, 0.f, 0.f};
    if (HAS_BIAS) {
#pragma unroll
        for (int ct = 0; ct < 4; ++ct) bia[ct] = bias[ct * 16 + lr];
    }
    float bsum[4] = {0.f, 0.f, 0.f, 0.f};
    float bsq[4] = {0.f, 0.f, 0.f, 0.f};
    const int wrow = wid * 32;
#pragma unroll
    for (int t = 0; t < 2; ++t) {
#pragma unroll
        for (int reg = 0; reg < 4; ++reg) {
            const int r = rowbase + wrow + t * 16 + lg * 4 + reg;
            const bool valid = r < N;
#pragma unroll
            for (int ct = 0; ct < 4; ++ct) {
                float v = acc[t][ct][reg];
                if (HAS_BIAS) v += bia[ct];
                if (MODE == 0) {
                    v = v > 0.f ? v : 0.01f * v;
                    if (valid) {
                        fout[(size_t)r * 64 + ct * 16 + lr] = f2bf(v);
                        bsum[ct] += v;
                        bsq[ct] += v * v;
                    }
                } else {
                    if (valid) {
                        v += skip[(size_t)r * 64 + ct * 16 + lr];
                        fout[(size_t)r * 64 + ct * 16 + lr] = f2bf(v);
                    }
                }
            }
        }
    }

    if (MODE == 0) {
        // reduce across lane groups (lanes differing in bits 4,5 share channel)
#pragma unroll
        for (int ct = 0; ct < 4; ++ct) {
            float s = bsum[ct], q = bsq[ct];
            s += __shfl_xor(s, 16); s += __shfl_xor(s, 32);
            q += __shfl_xor(q, 16); q += __shfl_xor(q, 32);
            if (lg == 0) {
                atomicAdd(&sred[ct * 16 + lr], s);
                atomicAdd(&sred[64 + ct * 16 + lr], q);
            }
        }
        __syncthreads();
        if (tid < 128) atomicAdd(&sums[tid], sred[tid]);
    }
}

// -------------- BN scale/shift from sums --------------
__global__ void finalize_kernel(const float* __restrict__ sums, const float* __restrict__ g,
                                const float* __restrict__ b, float invN, float* __restrict__ ss) {
    int c = threadIdx.x;
    float mean = sums[c] * invN;
    float var = sums[64 + c] * invN - mean * mean;
    float sc = g[c] * rsqrtf(var + 1e-5f);
    ss[c] = sc;
    ss[64 + c] = b[c] - mean * sc;
}

// -------------- final BN apply -> fp32 output --------------
__global__ void final_norm_kernel(const short* __restrict__ in, const float* __restrict__ ss,
                                  float* __restrict__ out, int total) {
    int e = (blockIdx.x * blockDim.x + threadIdx.x) * 8;
    if (e >= total) return;
    bf16x8 v = *(const bf16x8*)(in + e);
    int c0 = e & 63;
#pragma unroll
    for (int j = 0; j < 8; ++j)
        out[e + j] = bf2f(v[j]) * ss[c0 + j] + ss[64 + c0 + j];
}

extern "C" void kernel_launch(void* const* d_in, const int* in_sizes, int n_in,
                              void* d_out, int out_size, void* d_ws, size_t ws_size,
                              hipStream_t stream) {
    const float* x    = (const float*)d_in[0];
    const float* skip = (const float*)d_in[1];
    const int* nbr1 = (const int*)d_in[2];
    const int* nbrU = (const int*)d_in[3];
    const int* nbr2 = (const int*)d_in[4];
    const int* nbr3 = (const int*)d_in[5];
    const int* nbr4 = (const int*)d_in[6];
    const float* W1 = (const float*)d_in[7];
    const float* WU = (const float*)d_in[8];
    const float* W2 = (const float*)d_in[9];
    const float* W3 = (const float*)d_in[10];
    const float* W4 = (const float*)d_in[11];
    const float* g1 = (const float*)d_in[12]; const float* b1 = (const float*)d_in[13];
    const float* g2 = (const float*)d_in[14]; const float* b2 = (const float*)d_in[15];
    const float* g3 = (const float*)d_in[16]; const float* b3 = (const float*)d_in[17];
    const float* g4 = (const float*)d_in[18]; const float* b4 = (const float*)d_in[19];

    const int Nl = in_sizes[0] / 128;  // 120000
    const int Nu = in_sizes[1] / 64;   // 240000

    char* ws = (char*)d_ws;
    size_t off = 0;
    auto alloc = [&](size_t bytes) -> char* {
        char* p = ws + off;
        off += (bytes + 255) & ~(size_t)255;
        return p;
    };
    const size_t fbig = (size_t)Nu * 64 * 2;          // 30.72 MB
    const size_t xb = (size_t)Nl * 128 * 2;           // 30.72 MB
    short* A = (short*)alloc(xb > fbig ? xb : fbig);
    short* B = (short*)alloc(fbig);
    short* C = (short*)alloc(fbig);
    short* Wp1 = (short*)alloc((size_t)27 * 128 * 64 * 2);
    short* WpU = (short*)alloc((size_t)27 * 64 * 64 * 2);
    short* Wp2 = (short*)alloc((size_t)9 * 64 * 64 * 2);
    short* Wp3 = (short*)alloc((size_t)9 * 64 * 64 * 2);
    short* Wp4 = (short*)alloc((size_t)27 * 64 * 64 * 2);
    float* sums = (float*)alloc((512 + 192) * sizeof(float)); // 4x128 sums + 3x64 biases
    float* biasU = sums + 512;
    float* bias3 = sums + 576;
    float* bias4 = sums + 640;
    float* ss = (float*)alloc(4 * 128 * sizeof(float));

    hipMemsetAsync(sums, 0, (512 + 192) * sizeof(float), stream);

    // input cast + unscaled weight packs
    cast_kernel<<<(Nl * 128 / 8 + 255) / 256, 256, 0, stream>>>(x, A, Nl * 128);
    pack_w_kernel<<<(27 * 128 * 64 + 255) / 256, 256, 0, stream>>>(W1, Wp1, nullptr, 128, 27 * 128 * 64);
    pack_w_kernel<<<(9 * 64 * 64 + 255) / 256, 256, 0, stream>>>(W2, Wp2, nullptr, 64, 9 * 64 * 64);

    const int gl = (Nl + 127) / 128;
    const int gu = (Nu + 127) / 128;

    // stage 1: conv1 (Ci=128,K=27) + leaky + stats  [A -> B]
    conv_kernel<128, 27, 0, false><<<gl, 256, 0, stream>>>(A, nbr1, Wp1, nullptr, nullptr, B, Nl, sums + 0);
    finalize_kernel<<<1, 64, 0, stream>>>(sums + 0, g1, b1, 1.f / Nl, ss + 0);
    // fold BN1 into WU
    pack_w_kernel<<<(27 * 64 * 64 + 255) / 256, 256, 0, stream>>>(WU, WpU, ss + 0, 64, 27 * 64 * 64);
    bias_kernel<<<27, 64, 0, stream>>>(WU, ss + 0, 64, biasU);

    // stage 2: inverse conv (K=27) + bias + skip  [B -> C]
    conv_kernel<64, 27, 1, true><<<gu, 256, 0, stream>>>(B, nbrU, WpU, biasU, skip, C, Nu, nullptr);

    // stage 3: conv2 (K=9) + leaky + stats  [C -> A]
    conv_kernel<64, 9, 0, false><<<gu, 256, 0, stream>>>(C, nbr2, Wp2, nullptr, nullptr, A, Nu, sums + 128);
    finalize_kernel<<<1, 64, 0, stream>>>(sums + 128, g2, b2, 1.f / Nu, ss + 128);
    // fold BN2 into W3
    pack_w_kernel<<<(9 * 64 * 64 + 255) / 256, 256, 0, stream>>>(W3, Wp3, ss + 128, 64, 9 * 64 * 64);
    bias_kernel<<<9, 64, 0, stream>>>(W3, ss + 128, 64, bias3);

    // stage 4: conv3 (K=9) + bias + leaky + stats  [A -> B]
    conv_kernel<64, 9, 0, true><<<gu, 256, 0, stream>>>(A, nbr3, Wp3, bias3, nullptr, B, Nu, sums + 256);
    finalize_kernel<<<1, 64, 0, stream>>>(sums + 256, g3, b3, 1.f / Nu, ss + 256);
    // fold BN3 into W4
    pack_w_kernel<<<(27 * 64 * 64 + 255) / 256, 256, 0, stream>>>(W4, Wp4, ss + 256, 64, 27 * 64 * 64);
    bias_kernel<<<27, 64, 0, stream>>>(W4, ss + 256, 64, bias4);

    // stage 5: conv4 (K=27) + bias + leaky + stats  [B -> C]
    conv_kernel<64, 27, 0, true><<<gu, 256, 0, stream>>>(B, nbr4, Wp4, bias4, nullptr, C, Nu, sums + 384);
    finalize_kernel<<<1, 64, 0, stream>>>(sums + 384, g4, b4, 1.f / Nu, ss + 384);

    // final BN -> fp32 out
    final_norm_kernel<<<(Nu * 64 / 8 + 255) / 256, 256, 0, stream>>>(C, ss + 384, (float*)d_out, Nu * 64);
}

// Round 3
// 1275.018 us; speedup vs baseline: 1.0548x; 1.0035x over previous
//
#include <hip/hip_runtime.h>
#include <hip/hip_bf16.h>

// UpBlock: 5 sparse gather-GEMM convs + LeakyReLU + BatchNorm + residual.
// R3: fix vmcnt in-order drain — group-structured issue (weights -> gathers
// -> MFMAs per 4-chunk group) so MFMAs never wait on a just-issued weight
// load, preserving gather memory-level parallelism.

typedef __attribute__((ext_vector_type(8))) short bf16x8;
typedef __attribute__((ext_vector_type(4))) float f32x4;

__device__ __forceinline__ short f2bf(float f) {
    union { float f; unsigned u; } v; v.f = f;
    unsigned r = v.u + 0x7fffu + ((v.u >> 16) & 1u);
    return (short)(r >> 16);
}
__device__ __forceinline__ float bf2f(short s) {
    union { unsigned u; float f; } v;
    v.u = ((unsigned)(unsigned short)s) << 16;
    return v.f;
}

// ---------------- cast fp32 -> bf16 (vectorized 8/thread) ----------------
__global__ void cast_kernel(const float* __restrict__ in, short* __restrict__ out, int total) {
    int e = (blockIdx.x * blockDim.x + threadIdx.x) * 8;
    if (e >= total) return;
    bf16x8 r;
#pragma unroll
    for (int j = 0; j < 8; ++j) r[j] = f2bf(in[e + j]);
    *(bf16x8*)(out + e) = r;
}

// ------ pack W[k][ci][co] fp32 -> Wp[k][co][ci] bf16, optional ci-scale ------
__global__ void pack_w_kernel(const float* __restrict__ w, short* __restrict__ wp,
                              const float* __restrict__ ss, int CI, int total) {
    int t = blockIdx.x * blockDim.x + threadIdx.x;
    if (t >= total) return;
    int ci = t % CI;
    int rest = t / CI;
    int co = rest & 63;
    int k = rest >> 6;
    float v = w[(k * CI + ci) * 64 + co];
    if (ss) v *= ss[ci];
    wp[t] = f2bf(v);
}

// ------ bias[co] += sum_ci sh[ci]*W[k][ci][co]; one block per tap k ------
__global__ void bias_kernel(const float* __restrict__ w, const float* __restrict__ ss,
                            int CI, float* __restrict__ bias) {
    int k = blockIdx.x;
    int co = threadIdx.x;
    float acc = 0.f;
    for (int ci = 0; ci < CI; ++ci)
        acc += ss[64 + ci] * w[(k * CI + ci) * 64 + co];
    atomicAdd(&bias[co], acc);
}

// -------- one group of NC (k,s)-chunks: weights->gathers->MFMAs --------
// Issue order is the point: all weight frags (L2-hot) first, then all
// gathers (random, long latency), then MFMAs. Compiler's counted vmcnt
// keeps later gathers in flight across the MFMA block.
template <int CI, int NC>
__device__ __forceinline__ void do_group(
    const short* __restrict__ fin, const short* __restrict__ wpg,
    const int* __restrict__ sn0, const int* __restrict__ sn1,
    int lr, int lg, f32x4 (&acc)[2][4])
{
    constexpr int S = CI / 32;      // chunks per tap
    constexpr int TG = NC / S;      // taps in this group
    const int koff = lg * 8;

    int i0[TG], i1[TG];
#pragma unroll
    for (int t = 0; t < TG; ++t) { i0[t] = sn0[t]; i1[t] = sn1[t]; }

    bf16x8 wf[NC][4];
#pragma unroll
    for (int c = 0; c < NC; ++c) {
        const short* wb = wpg + (size_t)((c / S) * 64 + lr) * CI + (c % S) * 32 + koff;
#pragma unroll
        for (int ct = 0; ct < 4; ++ct)
            wf[c][ct] = *(const bf16x8*)(wb + (size_t)ct * 16 * CI);
    }

    bf16x8 sa[NC][2];
#pragma unroll
    for (int c = 0; c < NC; ++c) {
        const int t = c / S, s = c % S;
        sa[c][0] = *(const bf16x8*)(fin + (size_t)i0[t] * CI + s * 32 + koff);
        sa[c][1] = *(const bf16x8*)(fin + (size_t)i1[t] * CI + s * 32 + koff);
    }

#pragma unroll
    for (int c = 0; c < NC; ++c) {
#pragma unroll
        for (int ct = 0; ct < 4; ++ct) {
            acc[0][ct] = __builtin_amdgcn_mfma_f32_16x16x32_bf16(sa[c][0], wf[c][ct], acc[0][ct], 0, 0, 0);
            acc[1][ct] = __builtin_amdgcn_mfma_f32_16x16x32_bf16(sa[c][1], wf[c][ct], acc[1][ct], 0, 0, 0);
        }
    }
}

// ---------------- gather-GEMM conv ----------------
// 4 waves/block, 128 output rows/block, 32 rows/wave.
// MODE 0: v = leaky(acc[+bias]); write bf16; fused per-channel stats.
// MODE 1: v = acc + bias + skip; write bf16 (residual stage, no stats).
template <int CI, int KT, int MODE, bool HAS_BIAS>
__global__ __launch_bounds__(256) void conv_kernel(
    const short* __restrict__ fin, const int* __restrict__ nbr,
    const short* __restrict__ wp, const float* __restrict__ bias,
    const float* __restrict__ skip, short* __restrict__ fout,
    int N, float* __restrict__ sums)
{
    constexpr int S = CI / 32;               // 2 or 4
    constexpr int CPG = 4;                   // chunks per group
    constexpr int TPG = CPG / S;             // taps per group
    constexpr int NCH = KT * S;              // total chunks
    constexpr int FULLG = NCH / CPG;
    constexpr int TAILC = NCH % CPG;         // 0 or 2

    __shared__ int snbr[128 * KT];
    __shared__ float sred[128];

    const int tid = threadIdx.x;
    const int lane = tid & 63;
    const int wid = tid >> 6;
    const int lr = lane & 15;    // A row-in-tile / B,C col-in-tile
    const int lg = lane >> 4;    // lane group 0..3
    const int rowbase = blockIdx.x * 128;
    const int nrows = (N - rowbase < 128) ? (N - rowbase) : 128;

    for (int i = tid; i < nrows * KT; i += 256)
        snbr[i] = __builtin_nontemporal_load(&nbr[(size_t)rowbase * KT + i]);
    if (MODE == 0 && tid < 128) sred[tid] = 0.f;
    __syncthreads();

    const int rb0 = wid * 32 + lr;
    const int rb1 = wid * 32 + 16 + lr;
    const int row0 = (rb0 < nrows ? rb0 : nrows - 1);
    const int row1 = (rb1 < nrows ? rb1 : nrows - 1);
    const int* sn0 = &snbr[row0 * KT];
    const int* sn1 = &snbr[row1 * KT];

    f32x4 acc[2][4];
#pragma unroll
    for (int t = 0; t < 2; ++t)
#pragma unroll
        for (int c = 0; c < 4; ++c) acc[t][c] = (f32x4)(0.f);

    for (int g = 0; g < FULLG; ++g)
        do_group<CI, CPG>(fin, wp + (size_t)(g * TPG) * 64 * CI,
                          sn0 + g * TPG, sn1 + g * TPG, lr, lg, acc);
    if (TAILC)
        do_group<CI, (TAILC ? TAILC : CPG)>(fin, wp + (size_t)(FULLG * TPG) * 64 * CI,
                          sn0 + FULLG * TPG, sn1 + FULLG * TPG, lr, lg, acc);

    // epilogue: C/D layout col = ct*16+lr, row = wid*32 + t*16 + lg*4 + reg
    float bia[4] = {0.f, 0.f, 0.f, 0.f};
    if (HAS_BIAS) {
#pragma unroll
        for (int ct = 0; ct < 4; ++ct) bia[ct] = bias[ct * 16 + lr];
    }
    float bsum[4] = {0.f, 0.f, 0.f, 0.f};
    float bsq[4] = {0.f, 0.f, 0.f, 0.f};
    const int wrow = wid * 32;
#pragma unroll
    for (int t = 0; t < 2; ++t) {
#pragma unroll
        for (int reg = 0; reg < 4; ++reg) {
            const int r = rowbase + wrow + t * 16 + lg * 4 + reg;
            const bool valid = r < N;
#pragma unroll
            for (int ct = 0; ct < 4; ++ct) {
                float v = acc[t][ct][reg];
                if (HAS_BIAS) v += bia[ct];
                if (MODE == 0) {
                    v = v > 0.f ? v : 0.01f * v;
                    if (valid) {
                        fout[(size_t)r * 64 + ct * 16 + lr] = f2bf(v);
                        bsum[ct] += v;
                        bsq[ct] += v * v;
                    }
                } else {
                    if (valid) {
                        v += skip[(size_t)r * 64 + ct * 16 + lr];
                        fout[(size_t)r * 64 + ct * 16 + lr] = f2bf(v);
                    }
                }
            }
        }
    }

    if (MODE == 0) {
        // reduce across lane groups (lanes differing in bits 4,5 share channel)
#pragma unroll
        for (int ct = 0; ct < 4; ++ct) {
            float s = bsum[ct], q = bsq[ct];
            s += __shfl_xor(s, 16); s += __shfl_xor(s, 32);
            q += __shfl_xor(q, 16); q += __shfl_xor(q, 32);
            if (lg == 0) {
                atomicAdd(&sred[ct * 16 + lr], s);
                atomicAdd(&sred[64 + ct * 16 + lr], q);
            }
        }
        __syncthreads();
        if (tid < 128) atomicAdd(&sums[tid], sred[tid]);
    }
}

// -------------- BN scale/shift from sums --------------
__global__ void finalize_kernel(const float* __restrict__ sums, const float* __restrict__ g,
                                const float* __restrict__ b, float invN, float* __restrict__ ss) {
    int c = threadIdx.x;
    float mean = sums[c] * invN;
    float var = sums[64 + c] * invN - mean * mean;
    float sc = g[c] * rsqrtf(var + 1e-5f);
    ss[c] = sc;
    ss[64 + c] = b[c] - mean * sc;
}

// -------------- final BN apply -> fp32 output --------------
__global__ void final_norm_kernel(const short* __restrict__ in, const float* __restrict__ ss,
                                  float* __restrict__ out, int total) {
    int e = (blockIdx.x * blockDim.x + threadIdx.x) * 8;
    if (e >= total) return;
    bf16x8 v = *(const bf16x8*)(in + e);
    int c0 = e & 63;
#pragma unroll
    for (int j = 0; j < 8; ++j)
        out[e + j] = bf2f(v[j]) * ss[c0 + j] + ss[64 + c0 + j];
}

extern "C" void kernel_launch(void* const* d_in, const int* in_sizes, int n_in,
                              void* d_out, int out_size, void* d_ws, size_t ws_size,
                              hipStream_t stream) {
    const float* x    = (const float*)d_in[0];
    const float* skip = (const float*)d_in[1];
    const int* nbr1 = (const int*)d_in[2];
    const int* nbrU = (const int*)d_in[3];
    const int* nbr2 = (const int*)d_in[4];
    const int* nbr3 = (const int*)d_in[5];
    const int* nbr4 = (const int*)d_in[6];
    const float* W1 = (const float*)d_in[7];
    const float* WU = (const float*)d_in[8];
    const float* W2 = (const float*)d_in[9];
    const float* W3 = (const float*)d_in[10];
    const float* W4 = (const float*)d_in[11];
    const float* g1 = (const float*)d_in[12]; const float* b1 = (const float*)d_in[13];
    const float* g2 = (const float*)d_in[14]; const float* b2 = (const float*)d_in[15];
    const float* g3 = (const float*)d_in[16]; const float* b3 = (const float*)d_in[17];
    const float* g4 = (const float*)d_in[18]; const float* b4 = (const float*)d_in[19];

    const int Nl = in_sizes[0] / 128;  // 120000
    const int Nu = in_sizes[1] / 64;   // 240000

    char* ws = (char*)d_ws;
    size_t off = 0;
    auto alloc = [&](size_t bytes) -> char* {
        char* p = ws + off;
        off += (bytes + 255) & ~(size_t)255;
        return p;
    };
    const size_t fbig = (size_t)Nu * 64 * 2;          // 30.72 MB
    const size_t xb = (size_t)Nl * 128 * 2;           // 30.72 MB
    short* A = (short*)alloc(xb > fbig ? xb : fbig);
    short* B = (short*)alloc(fbig);
    short* C = (short*)alloc(fbig);
    short* Wp1 = (short*)alloc((size_t)27 * 128 * 64 * 2);
    short* WpU = (short*)alloc((size_t)27 * 64 * 64 * 2);
    short* Wp2 = (short*)alloc((size_t)9 * 64 * 64 * 2);
    short* Wp3 = (short*)alloc((size_t)9 * 64 * 64 * 2);
    short* Wp4 = (short*)alloc((size_t)27 * 64 * 64 * 2);
    float* sums = (float*)alloc((512 + 192) * sizeof(float)); // 4x128 sums + 3x64 biases
    float* biasU = sums + 512;
    float* bias3 = sums + 576;
    float* bias4 = sums + 640;
    float* ss = (float*)alloc(4 * 128 * sizeof(float));

    hipMemsetAsync(sums, 0, (512 + 192) * sizeof(float), stream);

    // input cast + unscaled weight packs
    cast_kernel<<<(Nl * 128 / 8 + 255) / 256, 256, 0, stream>>>(x, A, Nl * 128);
    pack_w_kernel<<<(27 * 128 * 64 + 255) / 256, 256, 0, stream>>>(W1, Wp1, nullptr, 128, 27 * 128 * 64);
    pack_w_kernel<<<(9 * 64 * 64 + 255) / 256, 256, 0, stream>>>(W2, Wp2, nullptr, 64, 9 * 64 * 64);

    const int gl = (Nl + 127) / 128;
    const int gu = (Nu + 127) / 128;

    // stage 1: conv1 (Ci=128,K=27) + leaky + stats  [A -> B]
    conv_kernel<128, 27, 0, false><<<gl, 256, 0, stream>>>(A, nbr1, Wp1, nullptr, nullptr, B, Nl, sums + 0);
    finalize_kernel<<<1, 64, 0, stream>>>(sums + 0, g1, b1, 1.f / Nl, ss + 0);
    // fold BN1 into WU
    pack_w_kernel<<<(27 * 64 * 64 + 255) / 256, 256, 0, stream>>>(WU, WpU, ss + 0, 64, 27 * 64 * 64);
    bias_kernel<<<27, 64, 0, stream>>>(WU, ss + 0, 64, biasU);

    // stage 2: inverse conv (K=27) + bias + skip  [B -> C]
    conv_kernel<64, 27, 1, true><<<gu, 256, 0, stream>>>(B, nbrU, WpU, biasU, skip, C, Nu, nullptr);

    // stage 3: conv2 (K=9) + leaky + stats  [C -> A]
    conv_kernel<64, 9, 0, false><<<gu, 256, 0, stream>>>(C, nbr2, Wp2, nullptr, nullptr, A, Nu, sums + 128);
    finalize_kernel<<<1, 64, 0, stream>>>(sums + 128, g2, b2, 1.f / Nu, ss + 128);
    // fold BN2 into W3
    pack_w_kernel<<<(9 * 64 * 64 + 255) / 256, 256, 0, stream>>>(W3, Wp3, ss + 128, 64, 9 * 64 * 64);
    bias_kernel<<<9, 64, 0, stream>>>(W3, ss + 128, 64, bias3);

    // stage 4: conv3 (K=9) + bias + leaky + stats  [A -> B]
    conv_kernel<64, 9, 0, true><<<gu, 256, 0, stream>>>(A, nbr3, Wp3, bias3, nullptr, B, Nu, sums + 256);
    finalize_kernel<<<1, 64, 0, stream>>>(sums + 256, g3, b3, 1.f / Nu, ss + 256);
    // fold BN3 into W4
    pack_w_kernel<<<(27 * 64 * 64 + 255) / 256, 256, 0, stream>>>(W4, Wp4, ss + 256, 64, 27 * 64 * 64);
    bias_kernel<<<27, 64, 0, stream>>>(W4, ss + 256, 64, bias4);

    // stage 5: conv4 (K=27) + bias + leaky + stats  [B -> C]
    conv_kernel<64, 27, 0, true><<<gu, 256, 0, stream>>>(B, nbr4, Wp4, bias4, nullptr, C, Nu, sums + 384);
    finalize_kernel<<<1, 64, 0, stream>>>(sums + 384, g4, b4, 1.f / Nu, ss + 384);

    // final BN -> fp32 out
    final_norm_kernel<<<(Nu * 64 / 8 + 255) / 256, 256, 0, stream>>>(C, ss + 384, (float*)d_out, Nu * 64);
}

// Round 4
// 791.893 us; speedup vs baseline: 1.6983x; 1.6101x over previous
//
#include <hip/hip_runtime.h>
#include <hip/hip_bf16.h>

// UpBlock: 5 sparse gather-GEMM convs + LeakyReLU + BatchNorm + residual.
// R4: all streaming loads via global_load_lds (zero VGPR, counted vmcnt,
// raw s_barrier). Per-wave double-buffered gather slots; block-shared
// XOR-swizzled weight tiles. CI=128 split into 2 CI-64 sub-taps.

typedef __attribute__((ext_vector_type(8))) short bf16x8;
typedef __attribute__((ext_vector_type(4))) float f32x4;

__device__ __forceinline__ short f2bf(float f) {
    union { float f; unsigned u; } v; v.f = f;
    unsigned r = v.u + 0x7fffu + ((v.u >> 16) & 1u);
    return (short)(r >> 16);
}
__device__ __forceinline__ float bf2f(short s) {
    union { unsigned u; float f; } v;
    v.u = ((unsigned)(unsigned short)s) << 16;
    return v.f;
}

__device__ __forceinline__ void gload16(const void* g, void* l) {
    __builtin_amdgcn_global_load_lds(
        (const __attribute__((address_space(1))) char*)g,
        (__attribute__((address_space(3))) char*)l, 16, 0, 0);
}

// ---------------- cast fp32 -> bf16 ----------------
__global__ void cast_kernel(const float* __restrict__ in, short* __restrict__ out, int total) {
    int e = (blockIdx.x * blockDim.x + threadIdx.x) * 8;
    if (e >= total) return;
    bf16x8 r;
#pragma unroll
    for (int j = 0; j < 8; ++j) r[j] = f2bf(in[e + j]);
    *(bf16x8*)(out + e) = r;
}

// ---- pack W[k][ci][co] -> Wp[tap'][co][ci'] bf16 (tap' = CI-64 sub-tap) ----
template <int H>  // H = CI/64
__global__ void pack_w_kernel(const float* __restrict__ w, short* __restrict__ wp,
                              const float* __restrict__ ss, int total) {
    int t = blockIdx.x * blockDim.x + threadIdx.x;
    if (t >= total) return;
    int ci2 = t & 63;            // ci within sub-tap
    int co = (t >> 6) & 63;
    int tap = t >> 12;
    int k = tap / H, half = tap % H;
    int ci = half * 64 + ci2;
    float v = w[(k * (64 * H) + ci) * 64 + co];
    if (ss) v *= ss[ci];
    wp[t] = f2bf(v);
}

// ------ bias[co] += sum_ci sh[ci]*W[k][ci][co]; one block per tap k ------
__global__ void bias_kernel(const float* __restrict__ w, const float* __restrict__ ss,
                            int CI, float* __restrict__ bias) {
    int k = blockIdx.x;
    int co = threadIdx.x;
    float acc = 0.f;
    for (int ci = 0; ci < CI; ++ci)
        acc += ss[64 + ci] * w[(k * CI + ci) * 64 + co];
    atomicAdd(&bias[co], acc);
}

// ================= gather-GEMM conv =================
template <int KTAB, int H>
struct ConvCtx {
    static constexpr int KT2 = KTAB * H;          // sub-taps
    static constexpr int P = (KT2 + 1) / 2;       // weight groups of 2
    const char* finb;
    const char* wpb;
    const int* snbr;      // LDS
    short* abufw;         // my wave's gather slots: 2 x 4096 B
    short (*wbufs)[8192]; // [2] weight double buffer, 16 KB each
    int row0, row1;       // per-lane clamped block rows
    int lane, lr, lg, wid;
    int CIB;              // feature row bytes (64*H*2)
};

template <int t, int KTAB, int H>
__device__ __forceinline__ void issue_gather(const ConvCtx<KTAB, H>& c) {
    constexpr int k = (H == 2) ? (t >> 1) : t;
    constexpr int halfoff = (H == 2) ? ((t & 1) * 128) : 0;
    int i0 = c.snbr[c.row0 * KTAB + k];
    int i1 = c.snbr[c.row1 * KTAB + k];
    const char* b0 = c.finb + (size_t)i0 * c.CIB + halfoff + c.lg * 16;
    const char* b1 = c.finb + (size_t)i1 * c.CIB + halfoff + c.lg * 16;
    short* d = c.abufw + (t & 1) * 2048;
    gload16(b0,      d);
    gload16(b0 + 64, d + 512);
    gload16(b1,      d + 1024);
    gload16(b1 + 64, d + 1536);
}

template <int p, int KTAB, int H>
__device__ __forceinline__ void issue_w(const ConvCtx<KTAB, H>& c, int wlaneoff) {
    const char* s = c.wpb + (size_t)p * 16384 + c.wid * 4096 + wlaneoff;
    short* d = c.wbufs[p & 1] + c.wid * 2048;
    gload16(s,        d);
    gload16(s + 1024, d + 512);
    gload16(s + 2048, d + 1024);
    gload16(s + 3072, d + 1536);
}

template <int t, int KTAB, int H>
__device__ __forceinline__ void tap_step(const ConvCtx<KTAB, H>& c, int wlaneoff,
                                         int woff0, int woff1, f32x4 (&acc)[2][4]) {
    constexpr int KT2 = ConvCtx<KTAB, H>::KT2;
    constexpr int P = ConvCtx<KTAB, H>::P;
    constexpr int NW = ((t & 1) == 0)
        ? (4 * ((t + 1 <= KT2 - 1) ? 1 : 0))
        : (4 * ((t + 1 <= KT2 - 1) ? 1 : 0) + 4 * (((t + 1) / 2 <= P - 1) ? 1 : 0));
    asm volatile("s_waitcnt vmcnt(%0)" :: "i"(NW) : "memory");
    if constexpr ((t & 1) == 0) {
        __builtin_amdgcn_s_barrier();
        if constexpr (t / 2 + 1 <= P - 1)
            issue_w<t / 2 + 1>(c, wlaneoff);
    }
    // A fragments (own slot, linear) + W fragments (swizzled)
    const short* ab = c.abufw + (t & 1) * 2048 + c.lane * 8;
    bf16x8 a00 = *(const bf16x8*)(ab);
    bf16x8 a01 = *(const bf16x8*)(ab + 512);
    bf16x8 a10 = *(const bf16x8*)(ab + 1024);
    bf16x8 a11 = *(const bf16x8*)(ab + 1536);
    const char* wt = (const char*)(c.wbufs[(t >> 1) & 1] + (t & 1) * 4096) + c.lr * 128;
    bf16x8 w0[4], w1[4];
#pragma unroll
    for (int ct = 0; ct < 4; ++ct) {
        w0[ct] = *(const bf16x8*)(wt + ct * 2048 + woff0);
        w1[ct] = *(const bf16x8*)(wt + ct * 2048 + woff1);
    }
    // LDS reads complete before reusing the gather slot
    asm volatile("s_waitcnt lgkmcnt(0)" ::: "memory");
    if constexpr (t + 2 <= KT2 - 1)
        issue_gather<t + 2>(c);
#pragma unroll
    for (int ct = 0; ct < 4; ++ct) {
        acc[0][ct] = __builtin_amdgcn_mfma_f32_16x16x32_bf16(a00, w0[ct], acc[0][ct], 0, 0, 0);
        acc[1][ct] = __builtin_amdgcn_mfma_f32_16x16x32_bf16(a10, w0[ct], acc[1][ct], 0, 0, 0);
        acc[0][ct] = __builtin_amdgcn_mfma_f32_16x16x32_bf16(a01, w1[ct], acc[0][ct], 0, 0, 0);
        acc[1][ct] = __builtin_amdgcn_mfma_f32_16x16x32_bf16(a11, w1[ct], acc[1][ct], 0, 0, 0);
    }
}

template <int t, int KTAB, int H>
__device__ __forceinline__ void run_taps(const ConvCtx<KTAB, H>& c, int wlaneoff,
                                         int woff0, int woff1, f32x4 (&acc)[2][4]) {
    tap_step<t>(c, wlaneoff, woff0, woff1, acc);
    if constexpr (t + 1 < ConvCtx<KTAB, H>::KT2)
        run_taps<t + 1>(c, wlaneoff, woff0, woff1, acc);
}

// MODE 0: leaky(acc[+bias]) -> bf16 + fused stats. MODE 1: acc+bias+skip -> bf16.
template <int KTAB, int H, int MODE, bool HAS_BIAS>
__global__ __launch_bounds__(256, 2) void conv_kernel(
    const short* __restrict__ fin, const int* __restrict__ nbr,
    const short* __restrict__ wp, const float* __restrict__ bias,
    const float* __restrict__ skip, short* __restrict__ fout,
    int N, float* __restrict__ sums)
{
    constexpr int KT2 = KTAB * H;
    __shared__ int snbr[128 * KTAB];
    __shared__ __align__(16) short abuf[4][2][2048];   // [wave][slot] 4 KB slots
    __shared__ __align__(16) short wbufs[2][8192];     // W double buffer, 16 KB
    __shared__ float sred[128];

    const int tid = threadIdx.x;
    const int lane = tid & 63;
    const int wid = tid >> 6;
    const int lr = lane & 15;
    const int lg = lane >> 4;
    const int rowbase = blockIdx.x * 128;
    const int nrows = (N - rowbase < 128) ? (N - rowbase) : 128;

    for (int i = tid; i < nrows * KTAB; i += 256)
        snbr[i] = __builtin_nontemporal_load(&nbr[(size_t)rowbase * KTAB + i]);
    if (MODE == 0 && tid < 128) sred[tid] = 0.f;
    __syncthreads();   // full drain: vmcnt accounting starts clean

    const int rb0 = wid * 32 + lr;
    const int rb1 = wid * 32 + 16 + lr;

    ConvCtx<KTAB, H> c;
    c.finb = (const char*)fin;
    c.wpb = (const char*)wp;
    c.snbr = snbr;
    c.abufw = &abuf[wid][0][0];
    c.wbufs = wbufs;
    c.row0 = (rb0 < nrows ? rb0 : nrows - 1);
    c.row1 = (rb1 < nrows ? rb1 : nrows - 1);
    c.lane = lane; c.lr = lr; c.lg = lg; c.wid = wid;
    c.CIB = 64 * H * 2;

    const int wlaneoff = (lane >> 3) * 128 + (((lane & 7) * 16) ^ ((lane >> 3) << 4));
    const int wsw = (lr & 7) << 4;
    const int woff0 = (lg * 16) ^ wsw;
    const int woff1 = (lg * 16 + 64) ^ wsw;

    f32x4 acc[2][4];
#pragma unroll
    for (int q = 0; q < 2; ++q)
#pragma unroll
        for (int cct = 0; cct < 4; ++cct) acc[q][cct] = (f32x4)(0.f);

    // prologue: W(0), g(0), g(1)
    issue_w<0>(c, wlaneoff);
    issue_gather<0>(c);
    issue_gather<1>(c);
    run_taps<0>(c, wlaneoff, woff0, woff1, acc);

    // ---------------- epilogue ----------------
    float bia[4] = {0.f, 0.f, 0.f, 0.f};
    if (HAS_BIAS) {
#pragma unroll
        for (int ct = 0; ct < 4; ++ct) bia[ct] = bias[ct * 16 + lr];
    }
    float bsum[4] = {0.f, 0.f, 0.f, 0.f};
    float bsq[4] = {0.f, 0.f, 0.f, 0.f};
    const int wrow = wid * 32;
#pragma unroll
    for (int q = 0; q < 2; ++q) {
#pragma unroll
        for (int reg = 0; reg < 4; ++reg) {
            const int r = rowbase + wrow + q * 16 + lg * 4 + reg;
            const bool valid = r < N;
#pragma unroll
            for (int ct = 0; ct < 4; ++ct) {
                float v = acc[q][ct][reg];
                if (HAS_BIAS) v += bia[ct];
                if (MODE == 0) {
                    v = v > 0.f ? v : 0.01f * v;
                    if (valid) {
                        fout[(size_t)r * 64 + ct * 16 + lr] = f2bf(v);
                        bsum[ct] += v;
                        bsq[ct] += v * v;
                    }
                } else {
                    if (valid) {
                        v += skip[(size_t)r * 64 + ct * 16 + lr];
                        fout[(size_t)r * 64 + ct * 16 + lr] = f2bf(v);
                    }
                }
            }
        }
    }

    if (MODE == 0) {
#pragma unroll
        for (int ct = 0; ct < 4; ++ct) {
            float s = bsum[ct], q = bsq[ct];
            s += __shfl_xor(s, 16); s += __shfl_xor(s, 32);
            q += __shfl_xor(q, 16); q += __shfl_xor(q, 32);
            if (lg == 0) {
                atomicAdd(&sred[ct * 16 + lr], s);
                atomicAdd(&sred[64 + ct * 16 + lr], q);
            }
        }
        __syncthreads();
        if (tid < 128) atomicAdd(&sums[tid], sred[tid]);
    }
}

// -------------- BN scale/shift from sums --------------
__global__ void finalize_kernel(const float* __restrict__ sums, const float* __restrict__ g,
                                const float* __restrict__ b, float invN, float* __restrict__ ss) {
    int c = threadIdx.x;
    float mean = sums[c] * invN;
    float var = sums[64 + c] * invN - mean * mean;
    float sc = g[c] * rsqrtf(var + 1e-5f);
    ss[c] = sc;
    ss[64 + c] = b[c] - mean * sc;
}

// -------------- final BN apply -> fp32 output --------------
__global__ void final_norm_kernel(const short* __restrict__ in, const float* __restrict__ ss,
                                  float* __restrict__ out, int total) {
    int e = (blockIdx.x * blockDim.x + threadIdx.x) * 8;
    if (e >= total) return;
    bf16x8 v = *(const bf16x8*)(in + e);
    int c0 = e & 63;
#pragma unroll
    for (int j = 0; j < 8; ++j)
        out[e + j] = bf2f(v[j]) * ss[c0 + j] + ss[64 + c0 + j];
}

extern "C" void kernel_launch(void* const* d_in, const int* in_sizes, int n_in,
                              void* d_out, int out_size, void* d_ws, size_t ws_size,
                              hipStream_t stream) {
    const float* x    = (const float*)d_in[0];
    const float* skip = (const float*)d_in[1];
    const int* nbr1 = (const int*)d_in[2];
    const int* nbrU = (const int*)d_in[3];
    const int* nbr2 = (const int*)d_in[4];
    const int* nbr3 = (const int*)d_in[5];
    const int* nbr4 = (const int*)d_in[6];
    const float* W1 = (const float*)d_in[7];
    const float* WU = (const float*)d_in[8];
    const float* W2 = (const float*)d_in[9];
    const float* W3 = (const float*)d_in[10];
    const float* W4 = (const float*)d_in[11];
    const float* g1 = (const float*)d_in[12]; const float* b1 = (const float*)d_in[13];
    const float* g2 = (const float*)d_in[14]; const float* b2 = (const float*)d_in[15];
    const float* g3 = (const float*)d_in[16]; const float* b3 = (const float*)d_in[17];
    const float* g4 = (const float*)d_in[18]; const float* b4 = (const float*)d_in[19];

    const int Nl = in_sizes[0] / 128;  // 120000
    const int Nu = in_sizes[1] / 64;   // 240000

    char* ws = (char*)d_ws;
    size_t off = 0;
    auto alloc = [&](size_t bytes) -> char* {
        char* p = ws + off;
        off += (bytes + 255) & ~(size_t)255;
        return p;
    };
    const size_t fbig = (size_t)Nu * 64 * 2;
    const size_t xb = (size_t)Nl * 128 * 2;
    short* A = (short*)alloc(xb > fbig ? xb : fbig);
    short* B = (short*)alloc(fbig);
    short* C = (short*)alloc(fbig);
    // weight buffers padded to even sub-tap count (8 KB per sub-tap)
    short* Wp1 = (short*)alloc((size_t)54 * 8192);
    short* WpU = (short*)alloc((size_t)28 * 8192);
    short* Wp2 = (short*)alloc((size_t)10 * 8192);
    short* Wp3 = (short*)alloc((size_t)10 * 8192);
    short* Wp4 = (short*)alloc((size_t)28 * 8192);
    float* sums = (float*)alloc((512 + 192) * sizeof(float));
    float* biasU = sums + 512;
    float* bias3 = sums + 576;
    float* bias4 = sums + 640;
    float* ss = (float*)alloc(4 * 128 * sizeof(float));

    hipMemsetAsync(sums, 0, (512 + 192) * sizeof(float), stream);

    cast_kernel<<<(Nl * 128 / 8 + 255) / 256, 256, 0, stream>>>(x, A, Nl * 128);
    pack_w_kernel<2><<<(54 * 4096 + 255) / 256, 256, 0, stream>>>(W1, Wp1, nullptr, 54 * 4096);
    pack_w_kernel<1><<<(9 * 4096 + 255) / 256, 256, 0, stream>>>(W2, Wp2, nullptr, 9 * 4096);

    const int gl = (Nl + 127) / 128;
    const int gu = (Nu + 127) / 128;

    // stage 1: conv1 (CI=128 -> H=2, K=27) + leaky + stats  [A -> B]
    conv_kernel<27, 2, 0, false><<<gl, 256, 0, stream>>>(A, nbr1, Wp1, nullptr, nullptr, B, Nl, sums + 0);
    finalize_kernel<<<1, 64, 0, stream>>>(sums + 0, g1, b1, 1.f / Nl, ss + 0);
    pack_w_kernel<1><<<(27 * 4096 + 255) / 256, 256, 0, stream>>>(WU, WpU, ss + 0, 27 * 4096);
    bias_kernel<<<27, 64, 0, stream>>>(WU, ss + 0, 64, biasU);

    // stage 2: inverse conv (K=27) + bias + skip  [B -> C]
    conv_kernel<27, 1, 1, true><<<gu, 256, 0, stream>>>(B, nbrU, WpU, biasU, skip, C, Nu, nullptr);

    // stage 3: conv2 (K=9) + leaky + stats  [C -> A]
    conv_kernel<9, 1, 0, false><<<gu, 256, 0, stream>>>(C, nbr2, Wp2, nullptr, nullptr, A, Nu, sums + 128);
    finalize_kernel<<<1, 64, 0, stream>>>(sums + 128, g2, b2, 1.f / Nu, ss + 128);
    pack_w_kernel<1><<<(9 * 4096 + 255) / 256, 256, 0, stream>>>(W3, Wp3, ss + 128, 9 * 4096);
    bias_kernel<<<9, 64, 0, stream>>>(W3, ss + 128, 64, bias3);

    // stage 4: conv3 (K=9) + bias + leaky + stats  [A -> B]
    conv_kernel<9, 1, 0, true><<<gu, 256, 0, stream>>>(A, nbr3, Wp3, bias3, nullptr, B, Nu, sums + 256);
    finalize_kernel<<<1, 64, 0, stream>>>(sums + 256, g3, b3, 1.f / Nu, ss + 256);
    pack_w_kernel<1><<<(27 * 4096 + 255) / 256, 256, 0, stream>>>(W4, Wp4, ss + 256, 27 * 4096);
    bias_kernel<<<27, 64, 0, stream>>>(W4, ss + 256, 64, bias4);

    // stage 5: conv4 (K=27) + bias + leaky + stats  [B -> C]
    conv_kernel<27, 1, 0, true><<<gu, 256, 0, stream>>>(B, nbr4, Wp4, bias4, nullptr, C, Nu, sums + 384);
    finalize_kernel<<<1, 64, 0, stream>>>(sums + 384, g4, b4, 1.f / Nu, ss + 384);

    final_norm_kernel<<<(Nu * 64 / 8 + 255) / 256, 256, 0, stream>>>(C, ss + 384, (float*)d_out, Nu * 64);
}